// Round 6
// baseline (154.140 us; speedup 1.0000x reference)
//
#include <hip/hip_runtime.h>
#include <hip/hip_bf16.h>

// Lightning attention, B=2 H=16 N=4096 D=128, BLOCK=128, nb=32.
// Pass 1 (la_kv):   per-chunk KV^T (bf16) -> kvws; dump v^T (bf16) -> vtws. [512 thr]
// Pass 2 (la_scan): in-place decay scan over chunks (x4 vec).               [256 thr]
// Pass 3 (la_out):  out = (q@k^T * intra)@v + diag(q_decay)*(q@S).          [256 thr]
//   Round-2 proven structure (64x64 wave tiles, one barrier) + vT/S fragments
//   from global bf16 ws + single 34KB LDS buffer -> 4 blocks/CU.

#define LDB   136   // LDS row stride in u16 (272B, 16B-aligned)
#define NB    32
#define HH    16
#define NSEQ  4096

typedef float  f32x4  __attribute__((ext_vector_type(4)));
typedef __bf16 bf16x8 __attribute__((ext_vector_type(8)));
typedef unsigned short u16x8 __attribute__((ext_vector_type(8)));
typedef unsigned short u16x4 __attribute__((ext_vector_type(4)));

__device__ __forceinline__ unsigned short f2bf(float f) {
  unsigned int u = __float_as_uint(f);
  unsigned int r = (u + 0x7fffu + ((u >> 16) & 1u)) >> 16;
  return (unsigned short)r;
}
__device__ __forceinline__ float bf2f(unsigned short h) {
  return __uint_as_float(((unsigned int)h) << 16);
}
__device__ __forceinline__ bf16x8 cvt8(float4 a, float4 b) {
  bf16x8 r;
  r[0] = (__bf16)a.x; r[1] = (__bf16)a.y; r[2] = (__bf16)a.z; r[3] = (__bf16)a.w;
  r[4] = (__bf16)b.x; r[5] = (__bf16)b.y; r[6] = (__bf16)b.z; r[7] = (__bf16)b.w;
  return r;
}

// 128x128 fp32 row-major [tau][d] -> LDS bf16 transposed [d][LDB], 512 threads.
__device__ __forceinline__ void stage_transpose512(const float* __restrict__ src,
                                                   unsigned short* dst, int tid) {
#pragma unroll
  for (int i = 0; i < 8; ++i) {
    int idx = i * 512 + tid;
    int d   = idx & 127;
    int tq  = idx >> 7;
    u16x4 w;
#pragma unroll
    for (int j = 0; j < 4; ++j)
      w[j] = f2bf(src[(tq * 4 + j) * 128 + d]);
    *reinterpret_cast<u16x4*>(dst + d * LDB + tq * 4) = w;
  }
}

// Same + scale column tau by exp(-sl*(128-tau))  (k_decay).
__device__ __forceinline__ void stage_transpose_scaled512(const float* __restrict__ src,
                                                          unsigned short* dst, int tid,
                                                          float sl) {
#pragma unroll
  for (int i = 0; i < 8; ++i) {
    int idx = i * 512 + tid;
    int d   = idx & 127;
    int tq  = idx >> 7;
    u16x4 w;
#pragma unroll
    for (int j = 0; j < 4; ++j) {
      int tau = tq * 4 + j;
      float kd = __expf(-sl * (float)(128 - tau));
      w[j] = f2bf(src[tau * 128 + d] * kd);
    }
    *reinterpret_cast<u16x4*>(dst + d * LDB + tq * 4) = w;
  }
}

// Pass 1: KVT_c[e][d] = sum_tau v[tau][e]*k[tau][d]*kd(tau) -> kvws; v^T -> vtws.
__global__ __launch_bounds__(512, 4) void la_kv(const float* __restrict__ k,
                                                const float* __restrict__ v,
                                                const float* __restrict__ s,
                                                unsigned short* __restrict__ vtws,
                                                unsigned short* __restrict__ kvws) {
  __shared__ __align__(16) unsigned short kTs[128 * LDB];
  __shared__ __align__(16) unsigned short vT[128 * LDB];
  const int tid = threadIdx.x;
  const int bid = blockIdx.x;
  const int c   = bid & (NB - 1);
  const int bh  = bid >> 5;
  const float sl = s[bh & (HH - 1)];
  const size_t base = ((size_t)bh * NSEQ + (size_t)c * 128) * 128;

  stage_transpose_scaled512(k + base, kTs, tid, sl);
  stage_transpose512(v + base, vT, tid);
  __syncthreads();

  const int wid = tid >> 6, lane = tid & 63;
  const int wr = (wid >> 1) * 32, wc = (wid & 1) * 64;
  const int lr = lane & 15, lg = lane >> 4;

  f32x4 acc[2][4];
#pragma unroll
  for (int m = 0; m < 2; ++m)
#pragma unroll
    for (int n = 0; n < 4; ++n)
      acc[m][n] = (f32x4)0.f;

  // KV^T += v^T @ (k*kd): A = vT[e][tau], BT = kTs[d][tau]
#pragma unroll
  for (int kk = 0; kk < 4; ++kk) {
    const int kb = kk * 32 + lg * 8;
    bf16x8 af[2], bf_[4];
#pragma unroll
    for (int m = 0; m < 2; ++m)
      af[m] = __builtin_bit_cast(bf16x8,
          *reinterpret_cast<const u16x8*>(vT + (wr + m * 16 + lr) * LDB + kb));
#pragma unroll
    for (int n = 0; n < 4; ++n)
      bf_[n] = __builtin_bit_cast(bf16x8,
          *reinterpret_cast<const u16x8*>(kTs + (wc + n * 16 + lr) * LDB + kb));
#pragma unroll
    for (int m = 0; m < 2; ++m)
#pragma unroll
      for (int n = 0; n < 4; ++n)
        acc[m][n] = __builtin_amdgcn_mfma_f32_16x16x32_bf16(af[m], bf_[n], acc[m][n], 0, 0, 0);
  }

  unsigned short* dst = kvws + ((size_t)bh * NB + c) * 16384;
#pragma unroll
  for (int m = 0; m < 2; ++m)
#pragma unroll
    for (int n = 0; n < 4; ++n)
#pragma unroll
      for (int r = 0; r < 4; ++r)
        dst[(wr + m * 16 + lg * 4 + r) * 128 + (wc + n * 16 + lr)] = f2bf(acc[m][n][r]);

  // dump v^T (coalesced 16B)
  unsigned short* vdst = vtws + ((size_t)bh * NB + c) * 16384;
#pragma unroll
  for (int i = 0; i < 4; ++i) {
    int linear = (i * 512 + tid) * 8;
    int r = linear >> 7, cc = linear & 127;
    *reinterpret_cast<u16x8*>(vdst + linear) =
        *reinterpret_cast<const u16x8*>(vT + r * LDB + cc);
  }
}

// Pass 2: in-place decay scan, 4 elements per thread. After: kvws[c] = S^T at chunk start.
__global__ __launch_bounds__(256) void la_scan(const float* __restrict__ s,
                                               unsigned short* __restrict__ kvws) {
  const int t   = blockIdx.x * 256 + threadIdx.x;
  const int bh  = t >> 12;
  const int de4 = (t & 4095) * 4;
  const float bd = __expf(-s[bh & (HH - 1)] * 128.f);
  unsigned short* p = kvws + (size_t)bh * NB * 16384 + de4;
  float st[4] = {0.f, 0.f, 0.f, 0.f};
#pragma unroll
  for (int c = 0; c < NB; ++c) {
    u16x4 w = *reinterpret_cast<u16x4*>(p + c * 16384);
    u16x4 o;
#pragma unroll
    for (int j = 0; j < 4; ++j) {
      float tmp = bf2f(w[j]);
      o[j] = f2bf(st[j]);
      st[j] = st[j] * bd + tmp;
    }
    *reinterpret_cast<u16x4*>(p + c * 16384) = o;
  }
}

// Pass 3: round-2 structure, 64x64 wave tiles, one barrier, single LDS buffer.
__global__ __launch_bounds__(256, 4) void la_out(const float* __restrict__ q,
                                                 const float* __restrict__ k,
                                                 const float* __restrict__ s,
                                                 const unsigned short* __restrict__ vtws,
                                                 const unsigned short* __restrict__ kvws,
                                                 float* __restrict__ out) {
  __shared__ __align__(16) unsigned short Pb[128 * LDB];
  const int tid = threadIdx.x;
  const int bid = blockIdx.x;
  const int c   = bid & (NB - 1);
  const int bh  = bid >> 5;
  const float sl = s[bh & (HH - 1)];
  const size_t base = ((size_t)bh * NSEQ + (size_t)c * 128) * 128;

  const int wid = tid >> 6, lane = tid & 63;
  const int wr = (wid >> 1) * 64, wc = (wid & 1) * 64;
  const int lr = lane & 15, lg = lane >> 4;

  const unsigned short* vch = vtws + ((size_t)bh * NB + c) * 16384;
  const unsigned short* Sp  = kvws + ((size_t)bh * NB + c) * 16384;

  // ---- scores = q @ k^T (fragments straight from global fp32) ----
  f32x4 accS[4][4];
#pragma unroll
  for (int m = 0; m < 4; ++m)
#pragma unroll
    for (int n = 0; n < 4; ++n)
      accS[m][n] = (f32x4)0.f;

  bf16x8 qf[4][4];  // [kk][m], reused for q@S
#pragma unroll
  for (int kk = 0; kk < 4; ++kk) {
    const int kb = kk * 32 + lg * 8;
#pragma unroll
    for (int m = 0; m < 4; ++m) {
      const float* p = q + base + (size_t)(wr + m * 16 + lr) * 128 + kb;
      qf[kk][m] = cvt8(*reinterpret_cast<const float4*>(p),
                       *reinterpret_cast<const float4*>(p + 4));
    }
    bf16x8 kf[4];
#pragma unroll
    for (int n = 0; n < 4; ++n) {
      const float* p = k + base + (size_t)(wc + n * 16 + lr) * 128 + kb;
      kf[n] = cvt8(*reinterpret_cast<const float4*>(p),
                   *reinterpret_cast<const float4*>(p + 4));
    }
#pragma unroll
    for (int m = 0; m < 4; ++m)
#pragma unroll
      for (int n = 0; n < 4; ++n)
        accS[m][n] = __builtin_amdgcn_mfma_f32_16x16x32_bf16(qf[kk][m], kf[n], accS[m][n], 0, 0, 0);
  }

  // ---- P = scores * intra_decay (causal) -> LDS ----
#pragma unroll
  for (int m = 0; m < 4; ++m)
#pragma unroll
    for (int n = 0; n < 4; ++n)
#pragma unroll
      for (int r = 0; r < 4; ++r) {
        int t  = wr + m * 16 + lg * 4 + r;
        int sc = wc + n * 16 + lr;
        float pv = (t >= sc) ? accS[m][n][r] * __expf(-sl * (float)(t - sc)) : 0.f;
        Pb[t * LDB + sc] = f2bf(pv);
      }

  // ---- oi = q @ S (S^T fragments from global bf16 ws; overlaps P LDS writes) ----
  f32x4 oi[4][4];
#pragma unroll
  for (int m = 0; m < 4; ++m)
#pragma unroll
    for (int n = 0; n < 4; ++n)
      oi[m][n] = (f32x4)0.f;

#pragma unroll
  for (int kk = 0; kk < 4; ++kk) {
    const int kb = kk * 32 + lg * 8;
    bf16x8 sf[4];
#pragma unroll
    for (int n = 0; n < 4; ++n)
      sf[n] = __builtin_bit_cast(bf16x8,
          *reinterpret_cast<const u16x8*>(Sp + (size_t)(wc + n * 16 + lr) * 128 + kb));
#pragma unroll
    for (int m = 0; m < 4; ++m)
#pragma unroll
      for (int n = 0; n < 4; ++n)
        oi[m][n] = __builtin_amdgcn_mfma_f32_16x16x32_bf16(qf[kk][m], sf[n], oi[m][n], 0, 0, 0);
  }

  // row-scale by q_decay
#pragma unroll
  for (int m = 0; m < 4; ++m)
#pragma unroll
    for (int r = 0; r < 4; ++r) {
      float qd = __expf(-sl * (float)(wr + m * 16 + lg * 4 + r));
#pragma unroll
      for (int n = 0; n < 4; ++n)
        oi[m][n][r] *= qd;
    }

  __syncthreads();  // P fully written by all waves

  // ---- oi += P @ v  (P rows from LDS, v^T fragments from global ws) ----
#pragma unroll
  for (int kk = 0; kk < 4; ++kk) {
    const int kb = kk * 32 + lg * 8;
    bf16x8 pa[4], vb[4];
#pragma unroll
    for (int m = 0; m < 4; ++m)
      pa[m] = __builtin_bit_cast(bf16x8,
          *reinterpret_cast<const u16x8*>(Pb + (wr + m * 16 + lr) * LDB + kb));
#pragma unroll
    for (int n = 0; n < 4; ++n)
      vb[n] = __builtin_bit_cast(bf16x8,
          *reinterpret_cast<const u16x8*>(vch + (size_t)(wc + n * 16 + lr) * 128 + kb));
#pragma unroll
    for (int m = 0; m < 4; ++m)
#pragma unroll
      for (int n = 0; n < 4; ++n)
        oi[m][n] = __builtin_amdgcn_mfma_f32_16x16x32_bf16(pa[m], vb[n], oi[m][n], 0, 0, 0);
  }

#pragma unroll
  for (int m = 0; m < 4; ++m)
#pragma unroll
    for (int n = 0; n < 4; ++n)
#pragma unroll
      for (int r = 0; r < 4; ++r)
        __builtin_nontemporal_store(oi[m][n][r],
            out + base + (size_t)(wr + m * 16 + lg * 4 + r) * 128 + (wc + n * 16 + lr));
}

extern "C" void kernel_launch(void* const* d_in, const int* in_sizes, int n_in,
                              void* d_out, int out_size, void* d_ws, size_t ws_size,
                              hipStream_t stream) {
  const float* q = (const float*)d_in[0];
  const float* k = (const float*)d_in[1];
  const float* v = (const float*)d_in[2];
  const float* s = (const float*)d_in[3];
  float* out = (float*)d_out;
  unsigned short* vtws = (unsigned short*)d_ws;                       // 32 MiB
  unsigned short* kvws = vtws + (size_t)32 * NB * 16384;              // 32 MiB

  la_kv<<<dim3(2 * HH * NB), dim3(512), 0, stream>>>(k, v, s, vtws, kvws);
  la_scan<<<dim3(2 * HH * 16384 / 4 / 256), dim3(256), 0, stream>>>(s, kvws);
  la_out<<<dim3(2 * HH * NB), dim3(256), 0, stream>>>(q, k, s, vtws, kvws, out);
}

// Round 7
// 121.200 us; speedup vs baseline: 1.2718x; 1.2718x over previous
//
#include <hip/hip_runtime.h>
#include <hip/hip_bf16.h>

// Lightning attention, B=2 H=16 N=4096 D=128, BLOCK=128, nb=32.
// Pass 1 (la_kv):   per-chunk KV^T (bf16) -> kvws; dump v^T (bf16) -> vtws. [512 thr]
// Pass 2 (la_scan): in-place decay scan over chunks (x4 vec).               [256 thr]
// Pass 3 (la_out):  out = (q@k^T * intra)@v + diag(q_decay)*(q@S).          [256 thr]
//   64x64 wave tiles, one barrier, single 34KB LDS buffer. Register pressure
//   kept ~110 by re-loading q fragments in the q@S phase (L2-hot) instead of
//   keeping qf[4][4] live. NO min-waves launch-bounds clamp (round-6 spill bug).

#define LDB   136   // LDS row stride in u16 (272B, 16B-aligned)
#define NB    32
#define HH    16
#define NSEQ  4096

typedef float  f32x4  __attribute__((ext_vector_type(4)));
typedef __bf16 bf16x8 __attribute__((ext_vector_type(8)));
typedef unsigned short u16x8 __attribute__((ext_vector_type(8)));
typedef unsigned short u16x4 __attribute__((ext_vector_type(4)));

__device__ __forceinline__ unsigned short f2bf(float f) {
  unsigned int u = __float_as_uint(f);
  unsigned int r = (u + 0x7fffu + ((u >> 16) & 1u)) >> 16;
  return (unsigned short)r;
}
__device__ __forceinline__ float bf2f(unsigned short h) {
  return __uint_as_float(((unsigned int)h) << 16);
}
__device__ __forceinline__ bf16x8 cvt8(float4 a, float4 b) {
  bf16x8 r;
  r[0] = (__bf16)a.x; r[1] = (__bf16)a.y; r[2] = (__bf16)a.z; r[3] = (__bf16)a.w;
  r[4] = (__bf16)b.x; r[5] = (__bf16)b.y; r[6] = (__bf16)b.z; r[7] = (__bf16)b.w;
  return r;
}

// 128x128 fp32 row-major [tau][d] -> LDS bf16 transposed [d][LDB], 512 threads.
__device__ __forceinline__ void stage_transpose512(const float* __restrict__ src,
                                                   unsigned short* dst, int tid) {
#pragma unroll
  for (int i = 0; i < 8; ++i) {
    int idx = i * 512 + tid;
    int d   = idx & 127;
    int tq  = idx >> 7;
    u16x4 w;
#pragma unroll
    for (int j = 0; j < 4; ++j)
      w[j] = f2bf(src[(tq * 4 + j) * 128 + d]);
    *reinterpret_cast<u16x4*>(dst + d * LDB + tq * 4) = w;
  }
}

// Same + scale column tau by exp(-sl*(128-tau))  (k_decay).
__device__ __forceinline__ void stage_transpose_scaled512(const float* __restrict__ src,
                                                          unsigned short* dst, int tid,
                                                          float sl) {
#pragma unroll
  for (int i = 0; i < 8; ++i) {
    int idx = i * 512 + tid;
    int d   = idx & 127;
    int tq  = idx >> 7;
    u16x4 w;
#pragma unroll
    for (int j = 0; j < 4; ++j) {
      int tau = tq * 4 + j;
      float kd = __expf(-sl * (float)(128 - tau));
      w[j] = f2bf(src[tau * 128 + d] * kd);
    }
    *reinterpret_cast<u16x4*>(dst + d * LDB + tq * 4) = w;
  }
}

// Pass 1: KVT_c[e][d] = sum_tau v[tau][e]*k[tau][d]*kd(tau) -> kvws; v^T -> vtws.
__global__ __launch_bounds__(512) void la_kv(const float* __restrict__ k,
                                             const float* __restrict__ v,
                                             const float* __restrict__ s,
                                             unsigned short* __restrict__ vtws,
                                             unsigned short* __restrict__ kvws) {
  __shared__ __align__(16) unsigned short kTs[128 * LDB];
  __shared__ __align__(16) unsigned short vT[128 * LDB];
  const int tid = threadIdx.x;
  const int bid = blockIdx.x;
  const int c   = bid & (NB - 1);
  const int bh  = bid >> 5;
  const float sl = s[bh & (HH - 1)];
  const size_t base = ((size_t)bh * NSEQ + (size_t)c * 128) * 128;

  stage_transpose_scaled512(k + base, kTs, tid, sl);
  stage_transpose512(v + base, vT, tid);
  __syncthreads();

  const int wid = tid >> 6, lane = tid & 63;
  const int wr = (wid >> 1) * 32, wc = (wid & 1) * 64;
  const int lr = lane & 15, lg = lane >> 4;

  f32x4 acc[2][4];
#pragma unroll
  for (int m = 0; m < 2; ++m)
#pragma unroll
    for (int n = 0; n < 4; ++n)
      acc[m][n] = (f32x4)0.f;

  // KV^T += v^T @ (k*kd): A = vT[e][tau], BT = kTs[d][tau]
#pragma unroll
  for (int kk = 0; kk < 4; ++kk) {
    const int kb = kk * 32 + lg * 8;
    bf16x8 af[2], bf_[4];
#pragma unroll
    for (int m = 0; m < 2; ++m)
      af[m] = __builtin_bit_cast(bf16x8,
          *reinterpret_cast<const u16x8*>(vT + (wr + m * 16 + lr) * LDB + kb));
#pragma unroll
    for (int n = 0; n < 4; ++n)
      bf_[n] = __builtin_bit_cast(bf16x8,
          *reinterpret_cast<const u16x8*>(kTs + (wc + n * 16 + lr) * LDB + kb));
#pragma unroll
    for (int m = 0; m < 2; ++m)
#pragma unroll
      for (int n = 0; n < 4; ++n)
        acc[m][n] = __builtin_amdgcn_mfma_f32_16x16x32_bf16(af[m], bf_[n], acc[m][n], 0, 0, 0);
  }

  unsigned short* dst = kvws + ((size_t)bh * NB + c) * 16384;
#pragma unroll
  for (int m = 0; m < 2; ++m)
#pragma unroll
    for (int n = 0; n < 4; ++n)
#pragma unroll
      for (int r = 0; r < 4; ++r)
        dst[(wr + m * 16 + lg * 4 + r) * 128 + (wc + n * 16 + lr)] = f2bf(acc[m][n][r]);

  // dump v^T (coalesced 16B)
  unsigned short* vdst = vtws + ((size_t)bh * NB + c) * 16384;
#pragma unroll
  for (int i = 0; i < 4; ++i) {
    int linear = (i * 512 + tid) * 8;
    int r = linear >> 7, cc = linear & 127;
    *reinterpret_cast<u16x8*>(vdst + linear) =
        *reinterpret_cast<const u16x8*>(vT + r * LDB + cc);
  }
}

// Pass 2: in-place decay scan, 4 elements per thread. After: kvws[c] = S^T at chunk start.
__global__ __launch_bounds__(256) void la_scan(const float* __restrict__ s,
                                               unsigned short* __restrict__ kvws) {
  const int t   = blockIdx.x * 256 + threadIdx.x;
  const int bh  = t >> 12;
  const int de4 = (t & 4095) * 4;
  const float bd = __expf(-s[bh & (HH - 1)] * 128.f);
  unsigned short* p = kvws + (size_t)bh * NB * 16384 + de4;
  float st[4] = {0.f, 0.f, 0.f, 0.f};
#pragma unroll
  for (int c = 0; c < NB; ++c) {
    u16x4 w = *reinterpret_cast<u16x4*>(p + c * 16384);
    u16x4 o;
#pragma unroll
    for (int j = 0; j < 4; ++j) {
      float tmp = bf2f(w[j]);
      o[j] = f2bf(st[j]);
      st[j] = st[j] * bd + tmp;
    }
    *reinterpret_cast<u16x4*>(p + c * 16384) = o;
  }
}

// Pass 3: 64x64 wave tiles, one barrier, single LDS buffer, low register pressure.
__global__ __launch_bounds__(256) void la_out(const float* __restrict__ q,
                                              const float* __restrict__ k,
                                              const float* __restrict__ s,
                                              const unsigned short* __restrict__ vtws,
                                              const unsigned short* __restrict__ kvws,
                                              float* __restrict__ out) {
  __shared__ __align__(16) unsigned short Pb[128 * LDB];
  const int tid = threadIdx.x;
  const int bid = blockIdx.x;
  const int c   = bid & (NB - 1);
  const int bh  = bid >> 5;
  const float sl = s[bh & (HH - 1)];
  const size_t base = ((size_t)bh * NSEQ + (size_t)c * 128) * 128;

  const int wid = tid >> 6, lane = tid & 63;
  const int wr = (wid >> 1) * 64, wc = (wid & 1) * 64;
  const int lr = lane & 15, lg = lane >> 4;

  const unsigned short* vch = vtws + ((size_t)bh * NB + c) * 16384;
  const unsigned short* Sp  = kvws + ((size_t)bh * NB + c) * 16384;

  // ---- phase A: scores = q @ k^T (transient qf/kf per kk; ~100 live regs) ----
  f32x4 accS[4][4];
#pragma unroll
  for (int m = 0; m < 4; ++m)
#pragma unroll
    for (int n = 0; n < 4; ++n)
      accS[m][n] = (f32x4)0.f;

#pragma unroll
  for (int kk = 0; kk < 4; ++kk) {
    const int kb = kk * 32 + lg * 8;
    bf16x8 qf[4], kf[4];
#pragma unroll
    for (int m = 0; m < 4; ++m) {
      const float* p = q + base + (size_t)(wr + m * 16 + lr) * 128 + kb;
      qf[m] = cvt8(*reinterpret_cast<const float4*>(p),
                   *reinterpret_cast<const float4*>(p + 4));
    }
#pragma unroll
    for (int n = 0; n < 4; ++n) {
      const float* p = k + base + (size_t)(wc + n * 16 + lr) * 128 + kb;
      kf[n] = cvt8(*reinterpret_cast<const float4*>(p),
                   *reinterpret_cast<const float4*>(p + 4));
    }
#pragma unroll
    for (int m = 0; m < 4; ++m)
#pragma unroll
      for (int n = 0; n < 4; ++n)
        accS[m][n] = __builtin_amdgcn_mfma_f32_16x16x32_bf16(qf[m], kf[n], accS[m][n], 0, 0, 0);
  }

  // ---- phase B: P = scores * intra_decay (causal) -> LDS (accS dies here) ----
#pragma unroll
  for (int m = 0; m < 4; ++m)
#pragma unroll
    for (int n = 0; n < 4; ++n)
#pragma unroll
      for (int r = 0; r < 4; ++r) {
        int t  = wr + m * 16 + lg * 4 + r;
        int sc = wc + n * 16 + lr;
        float pv = (t >= sc) ? accS[m][n][r] * __expf(-sl * (float)(t - sc)) : 0.f;
        Pb[t * LDB + sc] = f2bf(pv);
      }

  // ---- phase C: oi = q @ S (q fragments re-loaded, L2-hot; S^T from bf16 ws) ----
  f32x4 oi[4][4];
#pragma unroll
  for (int m = 0; m < 4; ++m)
#pragma unroll
    for (int n = 0; n < 4; ++n)
      oi[m][n] = (f32x4)0.f;

#pragma unroll
  for (int kk = 0; kk < 4; ++kk) {
    const int kb = kk * 32 + lg * 8;
    bf16x8 qf[4], sf[4];
#pragma unroll
    for (int m = 0; m < 4; ++m) {
      const float* p = q + base + (size_t)(wr + m * 16 + lr) * 128 + kb;
      qf[m] = cvt8(*reinterpret_cast<const float4*>(p),
                   *reinterpret_cast<const float4*>(p + 4));
    }
#pragma unroll
    for (int n = 0; n < 4; ++n)
      sf[n] = __builtin_bit_cast(bf16x8,
          *reinterpret_cast<const u16x8*>(Sp + (size_t)(wc + n * 16 + lr) * 128 + kb));
#pragma unroll
    for (int m = 0; m < 4; ++m)
#pragma unroll
      for (int n = 0; n < 4; ++n)
        oi[m][n] = __builtin_amdgcn_mfma_f32_16x16x32_bf16(qf[m], sf[n], oi[m][n], 0, 0, 0);
  }

  // row-scale by q_decay
#pragma unroll
  for (int m = 0; m < 4; ++m)
#pragma unroll
    for (int r = 0; r < 4; ++r) {
      float qd = __expf(-sl * (float)(wr + m * 16 + lg * 4 + r));
#pragma unroll
      for (int n = 0; n < 4; ++n)
        oi[m][n][r] *= qd;
    }

  __syncthreads();  // P fully written by all waves

  // ---- phase E: oi += P @ v (P rows from LDS, v^T fragments from bf16 ws) ----
#pragma unroll
  for (int kk = 0; kk < 4; ++kk) {
    const int kb = kk * 32 + lg * 8;
    bf16x8 pa[4], vb[4];
#pragma unroll
    for (int m = 0; m < 4; ++m)
      pa[m] = __builtin_bit_cast(bf16x8,
          *reinterpret_cast<const u16x8*>(Pb + (wr + m * 16 + lr) * LDB + kb));
#pragma unroll
    for (int n = 0; n < 4; ++n)
      vb[n] = __builtin_bit_cast(bf16x8,
          *reinterpret_cast<const u16x8*>(vch + (size_t)(wc + n * 16 + lr) * 128 + kb));
#pragma unroll
    for (int m = 0; m < 4; ++m)
#pragma unroll
      for (int n = 0; n < 4; ++n)
        oi[m][n] = __builtin_amdgcn_mfma_f32_16x16x32_bf16(pa[m], vb[n], oi[m][n], 0, 0, 0);
  }

#pragma unroll
  for (int m = 0; m < 4; ++m)
#pragma unroll
    for (int n = 0; n < 4; ++n)
#pragma unroll
      for (int r = 0; r < 4; ++r)
        __builtin_nontemporal_store(oi[m][n][r],
            out + base + (size_t)(wr + m * 16 + lg * 4 + r) * 128 + (wc + n * 16 + lr));
}

extern "C" void kernel_launch(void* const* d_in, const int* in_sizes, int n_in,
                              void* d_out, int out_size, void* d_ws, size_t ws_size,
                              hipStream_t stream) {
  const float* q = (const float*)d_in[0];
  const float* k = (const float*)d_in[1];
  const float* v = (const float*)d_in[2];
  const float* s = (const float*)d_in[3];
  float* out = (float*)d_out;
  unsigned short* vtws = (unsigned short*)d_ws;                       // 32 MiB
  unsigned short* kvws = vtws + (size_t)32 * NB * 16384;              // 32 MiB

  la_kv<<<dim3(2 * HH * NB), dim3(512), 0, stream>>>(k, v, s, vtws, kvws);
  la_scan<<<dim3(2 * HH * 16384 / 4 / 256), dim3(256), 0, stream>>>(s, kvws);
  la_out<<<dim3(2 * HH * NB), dim3(256), 0, stream>>>(q, k, s, vtws, kvws, out);
}

// Round 8
// 118.131 us; speedup vs baseline: 1.3048x; 1.0260x over previous
//
#include <hip/hip_runtime.h>
#include <hip/hip_bf16.h>

// Lightning attention, B=2 H=16 N=4096 D=128, BLOCK=128, nb=32.
// Pass 1 (la_kv):   per-chunk KV^T (bf16) -> kvws.                     [512 thr]
// Pass 2 (la_scan): in-place decay scan over chunks (x4 vec).          [256 thr]
// Pass 3 (la_out):  out = (q@k^T * intra)@v + diag(q_decay)*(q@S).     [512 thr]
//   Round-2 structure (vT staged LDS, S from bf16 ws, q/k direct global,
//   one barrier, Pb+vT LDS) at 8 waves/block, UNclamped launch bounds
//   (rounds 3/5/6 were spill-poisoned by __launch_bounds__(...,4)).

#define LDB   136   // LDS row stride in u16 (272B, 16B-aligned)
#define NB    32
#define HH    16
#define NSEQ  4096

typedef float  f32x4  __attribute__((ext_vector_type(4)));
typedef __bf16 bf16x8 __attribute__((ext_vector_type(8)));
typedef unsigned short u16x8 __attribute__((ext_vector_type(8)));
typedef unsigned short u16x4 __attribute__((ext_vector_type(4)));

__device__ __forceinline__ unsigned short f2bf(float f) {
  unsigned int u = __float_as_uint(f);
  unsigned int r = (u + 0x7fffu + ((u >> 16) & 1u)) >> 16;
  return (unsigned short)r;
}
__device__ __forceinline__ float bf2f(unsigned short h) {
  return __uint_as_float(((unsigned int)h) << 16);
}
__device__ __forceinline__ bf16x8 cvt8(float4 a, float4 b) {
  bf16x8 r;
  r[0] = (__bf16)a.x; r[1] = (__bf16)a.y; r[2] = (__bf16)a.z; r[3] = (__bf16)a.w;
  r[4] = (__bf16)b.x; r[5] = (__bf16)b.y; r[6] = (__bf16)b.z; r[7] = (__bf16)b.w;
  return r;
}

// 128x128 fp32 row-major [tau][d] -> LDS bf16 transposed [d][LDB], 512 threads.
__device__ __forceinline__ void stage_transpose512(const float* __restrict__ src,
                                                   unsigned short* dst, int tid) {
#pragma unroll
  for (int i = 0; i < 8; ++i) {
    int idx = i * 512 + tid;
    int d   = idx & 127;
    int tq  = idx >> 7;
    u16x4 w;
#pragma unroll
    for (int j = 0; j < 4; ++j)
      w[j] = f2bf(src[(tq * 4 + j) * 128 + d]);
    *reinterpret_cast<u16x4*>(dst + d * LDB + tq * 4) = w;
  }
}

// Same + scale column tau by exp(-sl*(128-tau))  (k_decay).
__device__ __forceinline__ void stage_transpose_scaled512(const float* __restrict__ src,
                                                          unsigned short* dst, int tid,
                                                          float sl) {
#pragma unroll
  for (int i = 0; i < 8; ++i) {
    int idx = i * 512 + tid;
    int d   = idx & 127;
    int tq  = idx >> 7;
    u16x4 w;
#pragma unroll
    for (int j = 0; j < 4; ++j) {
      int tau = tq * 4 + j;
      float kd = __expf(-sl * (float)(128 - tau));
      w[j] = f2bf(src[tau * 128 + d] * kd);
    }
    *reinterpret_cast<u16x4*>(dst + d * LDB + tq * 4) = w;
  }
}

// Pass 1: KVT_c[e][d] = sum_tau v[tau][e]*k[tau][d]*kd(tau) -> kvws (bf16).
__global__ __launch_bounds__(512) void la_kv(const float* __restrict__ k,
                                             const float* __restrict__ v,
                                             const float* __restrict__ s,
                                             unsigned short* __restrict__ kvws) {
  __shared__ __align__(16) unsigned short kTs[128 * LDB];
  __shared__ __align__(16) unsigned short vT[128 * LDB];
  const int tid = threadIdx.x;
  const int bid = blockIdx.x;
  const int c   = bid & (NB - 1);
  const int bh  = bid >> 5;
  const float sl = s[bh & (HH - 1)];
  const size_t base = ((size_t)bh * NSEQ + (size_t)c * 128) * 128;

  stage_transpose_scaled512(k + base, kTs, tid, sl);
  stage_transpose512(v + base, vT, tid);
  __syncthreads();

  const int wid = tid >> 6, lane = tid & 63;
  const int wr = (wid >> 1) * 32, wc = (wid & 1) * 64;
  const int lr = lane & 15, lg = lane >> 4;

  f32x4 acc[2][4];
#pragma unroll
  for (int m = 0; m < 2; ++m)
#pragma unroll
    for (int n = 0; n < 4; ++n)
      acc[m][n] = (f32x4)0.f;

  // KV^T += v^T @ (k*kd): A = vT[e][tau], BT = kTs[d][tau]
#pragma unroll
  for (int kk = 0; kk < 4; ++kk) {
    const int kb = kk * 32 + lg * 8;
    bf16x8 af[2], bf_[4];
#pragma unroll
    for (int m = 0; m < 2; ++m)
      af[m] = __builtin_bit_cast(bf16x8,
          *reinterpret_cast<const u16x8*>(vT + (wr + m * 16 + lr) * LDB + kb));
#pragma unroll
    for (int n = 0; n < 4; ++n)
      bf_[n] = __builtin_bit_cast(bf16x8,
          *reinterpret_cast<const u16x8*>(kTs + (wc + n * 16 + lr) * LDB + kb));
#pragma unroll
    for (int m = 0; m < 2; ++m)
#pragma unroll
      for (int n = 0; n < 4; ++n)
        acc[m][n] = __builtin_amdgcn_mfma_f32_16x16x32_bf16(af[m], bf_[n], acc[m][n], 0, 0, 0);
  }

  unsigned short* dst = kvws + ((size_t)bh * NB + c) * 16384;
#pragma unroll
  for (int m = 0; m < 2; ++m)
#pragma unroll
    for (int n = 0; n < 4; ++n)
#pragma unroll
      for (int r = 0; r < 4; ++r)
        dst[(wr + m * 16 + lg * 4 + r) * 128 + (wc + n * 16 + lr)] = f2bf(acc[m][n][r]);
}

// Pass 2: in-place decay scan, 4 elements per thread. After: kvws[c] = S^T at chunk start.
__global__ __launch_bounds__(256) void la_scan(const float* __restrict__ s,
                                               unsigned short* __restrict__ kvws) {
  const int t   = blockIdx.x * 256 + threadIdx.x;
  const int bh  = t >> 12;
  const int de4 = (t & 4095) * 4;
  const float bd = __expf(-s[bh & (HH - 1)] * 128.f);
  unsigned short* p = kvws + (size_t)bh * NB * 16384 + de4;
  float st[4] = {0.f, 0.f, 0.f, 0.f};
#pragma unroll
  for (int c = 0; c < NB; ++c) {
    u16x4 w = *reinterpret_cast<u16x4*>(p + c * 16384);
    u16x4 o;
#pragma unroll
    for (int j = 0; j < 4; ++j) {
      float tmp = bf2f(w[j]);
      o[j] = f2bf(st[j]);
      st[j] = st[j] * bd + tmp;
    }
    *reinterpret_cast<u16x4*>(p + c * 16384) = o;
  }
}

// Pass 3: 8 waves, 32x64 wave tiles, one barrier, Pb+vT LDS, no reg clamp.
__global__ __launch_bounds__(512) void la_out(const float* __restrict__ q,
                                              const float* __restrict__ k,
                                              const float* __restrict__ v,
                                              const float* __restrict__ s,
                                              const unsigned short* __restrict__ kvws,
                                              float* __restrict__ out) {
  __shared__ __align__(16) unsigned short Pb[128 * LDB];
  __shared__ __align__(16) unsigned short vT[128 * LDB];
  const int tid = threadIdx.x;
  const int bid = blockIdx.x;
  const int c   = bid & (NB - 1);
  const int bh  = bid >> 5;
  const float sl = s[bh & (HH - 1)];
  const size_t base = ((size_t)bh * NSEQ + (size_t)c * 128) * 128;

  // early coalesced staging of v^T (overlaps phase A's dependent loads)
  stage_transpose512(v + base, vT, tid);

  const int wid = tid >> 6, lane = tid & 63;
  const int wr = (wid >> 1) * 32, wc = (wid & 1) * 64;
  const int lr = lane & 15, lg = lane >> 4;

  const unsigned short* Sp = kvws + ((size_t)bh * NB + c) * 16384;

  // ---- phase A: scores = q @ k^T (fragments straight from global fp32) ----
  f32x4 accS[2][4];
#pragma unroll
  for (int m = 0; m < 2; ++m)
#pragma unroll
    for (int n = 0; n < 4; ++n)
      accS[m][n] = (f32x4)0.f;

  bf16x8 qf[4][2];  // [kk][m], kept live for q@S (32 VGPRs)
#pragma unroll
  for (int kk = 0; kk < 4; ++kk) {
    const int kb = kk * 32 + lg * 8;
#pragma unroll
    for (int m = 0; m < 2; ++m) {
      const float* p = q + base + (size_t)(wr + m * 16 + lr) * 128 + kb;
      qf[kk][m] = cvt8(*reinterpret_cast<const float4*>(p),
                       *reinterpret_cast<const float4*>(p + 4));
    }
    bf16x8 kf[4];
#pragma unroll
    for (int n = 0; n < 4; ++n) {
      const float* p = k + base + (size_t)(wc + n * 16 + lr) * 128 + kb;
      kf[n] = cvt8(*reinterpret_cast<const float4*>(p),
                   *reinterpret_cast<const float4*>(p + 4));
    }
#pragma unroll
    for (int m = 0; m < 2; ++m)
#pragma unroll
      for (int n = 0; n < 4; ++n)
        accS[m][n] = __builtin_amdgcn_mfma_f32_16x16x32_bf16(qf[kk][m], kf[n], accS[m][n], 0, 0, 0);
  }

  // ---- phase B: P = scores * intra_decay (causal) -> LDS (accS dies) ----
#pragma unroll
  for (int m = 0; m < 2; ++m)
#pragma unroll
    for (int n = 0; n < 4; ++n)
#pragma unroll
      for (int r = 0; r < 4; ++r) {
        int t  = wr + m * 16 + lg * 4 + r;
        int sc = wc + n * 16 + lr;
        float pv = (t >= sc) ? accS[m][n][r] * __expf(-sl * (float)(t - sc)) : 0.f;
        Pb[t * LDB + sc] = f2bf(pv);
      }

  // ---- phase C: oi = q @ S (S^T fragments from global bf16 ws) ----
  f32x4 oi[2][4];
#pragma unroll
  for (int m = 0; m < 2; ++m)
#pragma unroll
    for (int n = 0; n < 4; ++n)
      oi[m][n] = (f32x4)0.f;

#pragma unroll
  for (int kk = 0; kk < 4; ++kk) {
    const int kb = kk * 32 + lg * 8;
    bf16x8 sf[4];
#pragma unroll
    for (int n = 0; n < 4; ++n)
      sf[n] = __builtin_bit_cast(bf16x8,
          *reinterpret_cast<const u16x8*>(Sp + (size_t)(wc + n * 16 + lr) * 128 + kb));
#pragma unroll
    for (int m = 0; m < 2; ++m)
#pragma unroll
      for (int n = 0; n < 4; ++n)
        oi[m][n] = __builtin_amdgcn_mfma_f32_16x16x32_bf16(qf[kk][m], sf[n], oi[m][n], 0, 0, 0);
  }

  // row-scale by q_decay
#pragma unroll
  for (int m = 0; m < 2; ++m)
#pragma unroll
    for (int r = 0; r < 4; ++r) {
      float qd = __expf(-sl * (float)(wr + m * 16 + lg * 4 + r));
#pragma unroll
      for (int n = 0; n < 4; ++n)
        oi[m][n][r] *= qd;
    }

  __syncthreads();  // P fully written by all waves + vT staged

  // ---- phase E: oi += P @ v (P rows + v^T cols from LDS) ----
#pragma unroll
  for (int kk = 0; kk < 4; ++kk) {
    const int kb = kk * 32 + lg * 8;
    bf16x8 pa[2], vb[4];
#pragma unroll
    for (int m = 0; m < 2; ++m)
      pa[m] = __builtin_bit_cast(bf16x8,
          *reinterpret_cast<const u16x8*>(Pb + (wr + m * 16 + lr) * LDB + kb));
#pragma unroll
    for (int n = 0; n < 4; ++n)
      vb[n] = __builtin_bit_cast(bf16x8,
          *reinterpret_cast<const u16x8*>(vT + (wc + n * 16 + lr) * LDB + kb));
#pragma unroll
    for (int m = 0; m < 2; ++m)
#pragma unroll
      for (int n = 0; n < 4; ++n)
        oi[m][n] = __builtin_amdgcn_mfma_f32_16x16x32_bf16(pa[m], vb[n], oi[m][n], 0, 0, 0);
  }

#pragma unroll
  for (int m = 0; m < 2; ++m)
#pragma unroll
    for (int n = 0; n < 4; ++n)
#pragma unroll
      for (int r = 0; r < 4; ++r)
        out[base + (size_t)(wr + m * 16 + lg * 4 + r) * 128 + (wc + n * 16 + lr)] =
            oi[m][n][r];
}

extern "C" void kernel_launch(void* const* d_in, const int* in_sizes, int n_in,
                              void* d_out, int out_size, void* d_ws, size_t ws_size,
                              hipStream_t stream) {
  const float* q = (const float*)d_in[0];
  const float* k = (const float*)d_in[1];
  const float* v = (const float*)d_in[2];
  const float* s = (const float*)d_in[3];
  float* out = (float*)d_out;
  unsigned short* kvws = (unsigned short*)d_ws;  // 32 MiB bf16

  la_kv<<<dim3(2 * HH * NB), dim3(512), 0, stream>>>(k, v, s, kvws);
  la_scan<<<dim3(2 * HH * 16384 / 4 / 256), dim3(256), 0, stream>>>(s, kvws);
  la_out<<<dim3(2 * HH * NB), dim3(512), 0, stream>>>(q, k, v, s, kvws, out);
}

// Round 9
// 111.365 us; speedup vs baseline: 1.3841x; 1.0608x over previous
//
#include <hip/hip_runtime.h>
#include <hip/hip_bf16.h>

// Lightning attention, B=2 H=16 N=4096 D=128, BLOCK=128, nb=32.
// Pass 1 (la_kv):   per-chunk KV^T (bf16) -> kvws.                     [512 thr]
// Pass 2 (la_scan): in-place decay scan over chunks (x4 vec).          [256 thr]
// Pass 3 (la_out):  out = (q@k^T * intra)@v + diag(q_decay)*(q@S).     [256 thr]
//   Round-2 anchor (64x64 wave tiles, vT in LDS, qf live, one barrier) with
//   ALL S^T fragment loads hoisted to kernel start and q@S computed FIRST,
//   so every long-latency load is in flight before the MFMA chains.

#define LDB   136   // LDS row stride in u16 (272B, 16B-aligned)
#define NB    32
#define HH    16
#define NSEQ  4096

typedef float  f32x4  __attribute__((ext_vector_type(4)));
typedef __bf16 bf16x8 __attribute__((ext_vector_type(8)));
typedef unsigned short u16x8 __attribute__((ext_vector_type(8)));
typedef unsigned short u16x4 __attribute__((ext_vector_type(4)));

__device__ __forceinline__ unsigned short f2bf(float f) {
  unsigned int u = __float_as_uint(f);
  unsigned int r = (u + 0x7fffu + ((u >> 16) & 1u)) >> 16;
  return (unsigned short)r;
}
__device__ __forceinline__ float bf2f(unsigned short h) {
  return __uint_as_float(((unsigned int)h) << 16);
}
__device__ __forceinline__ bf16x8 cvt8(float4 a, float4 b) {
  bf16x8 r;
  r[0] = (__bf16)a.x; r[1] = (__bf16)a.y; r[2] = (__bf16)a.z; r[3] = (__bf16)a.w;
  r[4] = (__bf16)b.x; r[5] = (__bf16)b.y; r[6] = (__bf16)b.z; r[7] = (__bf16)b.w;
  return r;
}

// 128x128 fp32 row-major [tau][d] -> LDS bf16 transposed [d][LDB], 512 threads.
__device__ __forceinline__ void stage_transpose512(const float* __restrict__ src,
                                                   unsigned short* dst, int tid) {
#pragma unroll
  for (int i = 0; i < 8; ++i) {
    int idx = i * 512 + tid;
    int d   = idx & 127;
    int tq  = idx >> 7;
    u16x4 w;
#pragma unroll
    for (int j = 0; j < 4; ++j)
      w[j] = f2bf(src[(tq * 4 + j) * 128 + d]);
    *reinterpret_cast<u16x4*>(dst + d * LDB + tq * 4) = w;
  }
}

// 256-thread variant.
__device__ __forceinline__ void stage_transpose256(const float* __restrict__ src,
                                                   unsigned short* dst, int tid) {
#pragma unroll
  for (int i = 0; i < 16; ++i) {
    int idx = i * 256 + tid;
    int d   = idx & 127;
    int tq  = idx >> 7;
    u16x4 w;
#pragma unroll
    for (int j = 0; j < 4; ++j)
      w[j] = f2bf(src[(tq * 4 + j) * 128 + d]);
    *reinterpret_cast<u16x4*>(dst + d * LDB + tq * 4) = w;
  }
}

// 512-thread transpose + scale column tau by exp(-sl*(128-tau))  (k_decay).
__device__ __forceinline__ void stage_transpose_scaled512(const float* __restrict__ src,
                                                          unsigned short* dst, int tid,
                                                          float sl) {
#pragma unroll
  for (int i = 0; i < 8; ++i) {
    int idx = i * 512 + tid;
    int d   = idx & 127;
    int tq  = idx >> 7;
    u16x4 w;
#pragma unroll
    for (int j = 0; j < 4; ++j) {
      int tau = tq * 4 + j;
      float kd = __expf(-sl * (float)(128 - tau));
      w[j] = f2bf(src[tau * 128 + d] * kd);
    }
    *reinterpret_cast<u16x4*>(dst + d * LDB + tq * 4) = w;
  }
}

// Pass 1: KVT_c[e][d] = sum_tau v[tau][e]*k[tau][d]*kd(tau) -> kvws (bf16).
__global__ __launch_bounds__(512) void la_kv(const float* __restrict__ k,
                                             const float* __restrict__ v,
                                             const float* __restrict__ s,
                                             unsigned short* __restrict__ kvws) {
  __shared__ __align__(16) unsigned short kTs[128 * LDB];
  __shared__ __align__(16) unsigned short vT[128 * LDB];
  const int tid = threadIdx.x;
  const int bid = blockIdx.x;
  const int c   = bid & (NB - 1);
  const int bh  = bid >> 5;
  const float sl = s[bh & (HH - 1)];
  const size_t base = ((size_t)bh * NSEQ + (size_t)c * 128) * 128;

  stage_transpose_scaled512(k + base, kTs, tid, sl);
  stage_transpose512(v + base, vT, tid);
  __syncthreads();

  const int wid = tid >> 6, lane = tid & 63;
  const int wr = (wid >> 1) * 32, wc = (wid & 1) * 64;
  const int lr = lane & 15, lg = lane >> 4;

  f32x4 acc[2][4];
#pragma unroll
  for (int m = 0; m < 2; ++m)
#pragma unroll
    for (int n = 0; n < 4; ++n)
      acc[m][n] = (f32x4)0.f;

  // KV^T += v^T @ (k*kd): A = vT[e][tau], BT = kTs[d][tau]
#pragma unroll
  for (int kk = 0; kk < 4; ++kk) {
    const int kb = kk * 32 + lg * 8;
    bf16x8 af[2], bf_[4];
#pragma unroll
    for (int m = 0; m < 2; ++m)
      af[m] = __builtin_bit_cast(bf16x8,
          *reinterpret_cast<const u16x8*>(vT + (wr + m * 16 + lr) * LDB + kb));
#pragma unroll
    for (int n = 0; n < 4; ++n)
      bf_[n] = __builtin_bit_cast(bf16x8,
          *reinterpret_cast<const u16x8*>(kTs + (wc + n * 16 + lr) * LDB + kb));
#pragma unroll
    for (int m = 0; m < 2; ++m)
#pragma unroll
      for (int n = 0; n < 4; ++n)
        acc[m][n] = __builtin_amdgcn_mfma_f32_16x16x32_bf16(af[m], bf_[n], acc[m][n], 0, 0, 0);
  }

  unsigned short* dst = kvws + ((size_t)bh * NB + c) * 16384;
#pragma unroll
  for (int m = 0; m < 2; ++m)
#pragma unroll
    for (int n = 0; n < 4; ++n)
#pragma unroll
      for (int r = 0; r < 4; ++r)
        dst[(wr + m * 16 + lg * 4 + r) * 128 + (wc + n * 16 + lr)] = f2bf(acc[m][n][r]);
}

// Pass 2: in-place decay scan, 4 elements per thread. After: kvws[c] = S^T at chunk start.
__global__ __launch_bounds__(256) void la_scan(const float* __restrict__ s,
                                               unsigned short* __restrict__ kvws) {
  const int t   = blockIdx.x * 256 + threadIdx.x;
  const int bh  = t >> 12;
  const int de4 = (t & 4095) * 4;
  const float bd = __expf(-s[bh & (HH - 1)] * 128.f);
  unsigned short* p = kvws + (size_t)bh * NB * 16384 + de4;
  float st[4] = {0.f, 0.f, 0.f, 0.f};
#pragma unroll
  for (int c = 0; c < NB; ++c) {
    u16x4 w = *reinterpret_cast<u16x4*>(p + c * 16384);
    u16x4 o;
#pragma unroll
    for (int j = 0; j < 4; ++j) {
      float tmp = bf2f(w[j]);
      o[j] = f2bf(st[j]);
      st[j] = st[j] * bd + tmp;
    }
    *reinterpret_cast<u16x4*>(p + c * 16384) = o;
  }
}

// Pass 3: 4 waves, 64x64 tiles, one barrier; S loads hoisted, q@S computed first.
__global__ __launch_bounds__(256) void la_out(const float* __restrict__ q,
                                              const float* __restrict__ k,
                                              const float* __restrict__ v,
                                              const float* __restrict__ s,
                                              const unsigned short* __restrict__ kvws,
                                              float* __restrict__ out) {
  __shared__ __align__(16) unsigned short Pb[128 * LDB];
  __shared__ __align__(16) unsigned short vT[128 * LDB];
  const int tid = threadIdx.x;
  const int bid = blockIdx.x;
  const int c   = bid & (NB - 1);
  const int bh  = bid >> 5;
  const float sl = s[bh & (HH - 1)];
  const size_t base = ((size_t)bh * NSEQ + (size_t)c * 128) * 128;

  // earliest: coalesced v^T staging burst (independent of everything below)
  stage_transpose256(v + base, vT, tid);

  const int wid = tid >> 6, lane = tid & 63;
  const int wr = (wid >> 1) * 64, wc = (wid & 1) * 64;
  const int lr = lane & 15, lg = lane >> 4;

  const unsigned short* Sp = kvws + ((size_t)bh * NB + c) * 16384;

  // ---- hoisted loads: all S^T fragments + all q fragments ----
  bf16x8 sf[4][4];  // [kk][n], 64 VGPR, dies after q@S
#pragma unroll
  for (int kk = 0; kk < 4; ++kk) {
    const int kb = kk * 32 + lg * 8;
#pragma unroll
    for (int n = 0; n < 4; ++n)
      sf[kk][n] = __builtin_bit_cast(bf16x8,
          *reinterpret_cast<const u16x8*>(Sp + (size_t)(wc + n * 16 + lr) * 128 + kb));
  }
  bf16x8 qf[4][4];  // [kk][m], 64 VGPR, live for both matmuls
#pragma unroll
  for (int kk = 0; kk < 4; ++kk) {
    const int kb = kk * 32 + lg * 8;
#pragma unroll
    for (int m = 0; m < 4; ++m) {
      const float* p = q + base + (size_t)(wr + m * 16 + lr) * 128 + kb;
      qf[kk][m] = cvt8(*reinterpret_cast<const float4*>(p),
                       *reinterpret_cast<const float4*>(p + 4));
    }
  }

  // ---- phase C first: oi = q @ S (loads already in flight) ----
  f32x4 oi[4][4];
#pragma unroll
  for (int m = 0; m < 4; ++m)
#pragma unroll
    for (int n = 0; n < 4; ++n)
      oi[m][n] = (f32x4)0.f;

#pragma unroll
  for (int kk = 0; kk < 4; ++kk)
#pragma unroll
    for (int m = 0; m < 4; ++m)
#pragma unroll
      for (int n = 0; n < 4; ++n)
        oi[m][n] = __builtin_amdgcn_mfma_f32_16x16x32_bf16(qf[kk][m], sf[kk][n], oi[m][n], 0, 0, 0);

  // row-scale by q_decay (sf dead, accS not yet live)
#pragma unroll
  for (int m = 0; m < 4; ++m)
#pragma unroll
    for (int r = 0; r < 4; ++r) {
      float qd = __expf(-sl * (float)(wr + m * 16 + lg * 4 + r));
#pragma unroll
      for (int n = 0; n < 4; ++n)
        oi[m][n][r] *= qd;
    }

  // ---- phase A: accS = q @ k^T (kf transient per kk) ----
  f32x4 accS[4][4];
#pragma unroll
  for (int m = 0; m < 4; ++m)
#pragma unroll
    for (int n = 0; n < 4; ++n)
      accS[m][n] = (f32x4)0.f;

#pragma unroll
  for (int kk = 0; kk < 4; ++kk) {
    const int kb = kk * 32 + lg * 8;
    bf16x8 kf[4];
#pragma unroll
    for (int n = 0; n < 4; ++n) {
      const float* p = k + base + (size_t)(wc + n * 16 + lr) * 128 + kb;
      kf[n] = cvt8(*reinterpret_cast<const float4*>(p),
                   *reinterpret_cast<const float4*>(p + 4));
    }
#pragma unroll
    for (int m = 0; m < 4; ++m)
#pragma unroll
      for (int n = 0; n < 4; ++n)
        accS[m][n] = __builtin_amdgcn_mfma_f32_16x16x32_bf16(qf[kk][m], kf[n], accS[m][n], 0, 0, 0);
  }

  // ---- phase B: P = scores * intra_decay (causal) -> LDS ----
#pragma unroll
  for (int m = 0; m < 4; ++m)
#pragma unroll
    for (int n = 0; n < 4; ++n)
#pragma unroll
      for (int r = 0; r < 4; ++r) {
        int t  = wr + m * 16 + lg * 4 + r;
        int sc = wc + n * 16 + lr;
        float pv = (t >= sc) ? accS[m][n][r] * __expf(-sl * (float)(t - sc)) : 0.f;
        Pb[t * LDB + sc] = f2bf(pv);
      }

  __syncthreads();  // P fully written by all waves + vT staged

  // ---- phase E: oi += P @ v (P rows + v^T cols from LDS) ----
#pragma unroll
  for (int kk = 0; kk < 4; ++kk) {
    const int kb = kk * 32 + lg * 8;
    bf16x8 pa[4], vb[4];
#pragma unroll
    for (int m = 0; m < 4; ++m)
      pa[m] = __builtin_bit_cast(bf16x8,
          *reinterpret_cast<const u16x8*>(Pb + (wr + m * 16 + lr) * LDB + kb));
#pragma unroll
    for (int n = 0; n < 4; ++n)
      vb[n] = __builtin_bit_cast(bf16x8,
          *reinterpret_cast<const u16x8*>(vT + (wc + n * 16 + lr) * LDB + kb));
#pragma unroll
    for (int m = 0; m < 4; ++m)
#pragma unroll
      for (int n = 0; n < 4; ++n)
        oi[m][n] = __builtin_amdgcn_mfma_f32_16x16x32_bf16(pa[m], vb[n], oi[m][n], 0, 0, 0);
  }

#pragma unroll
  for (int m = 0; m < 4; ++m)
#pragma unroll
    for (int n = 0; n < 4; ++n)
#pragma unroll
      for (int r = 0; r < 4; ++r)
        out[base + (size_t)(wr + m * 16 + lg * 4 + r) * 128 + (wc + n * 16 + lr)] =
            oi[m][n][r];
}

extern "C" void kernel_launch(void* const* d_in, const int* in_sizes, int n_in,
                              void* d_out, int out_size, void* d_ws, size_t ws_size,
                              hipStream_t stream) {
  const float* q = (const float*)d_in[0];
  const float* k = (const float*)d_in[1];
  const float* v = (const float*)d_in[2];
  const float* s = (const float*)d_in[3];
  float* out = (float*)d_out;
  unsigned short* kvws = (unsigned short*)d_ws;  // 32 MiB bf16

  la_kv<<<dim3(2 * HH * NB), dim3(512), 0, stream>>>(k, v, s, kvws);
  la_scan<<<dim3(2 * HH * 16384 / 4 / 256), dim3(256), 0, stream>>>(s, kvws);
  la_out<<<dim3(2 * HH * NB), dim3(256), 0, stream>>>(q, k, v, s, kvws, out);
}